// Round 3
// baseline (467.766 us; speedup 1.0000x reference)
//
#include <hip/hip_runtime.h>

// out[i,j,k] = image[i,j,perm[i,j,k]], C=3, W=H=4096 (50.3M elems, x4B).
// Memory-bound gather. R1 showed VGPR=16 -> loads serialized, latency-bound
// at 4.0 TB/s effective. R2/R3: 2 independent 48B chunks/thread, all 12
// dwordx4 loads in flight before compute; NT stores keep the write-once
// output stream from evicting input lines in L2/L3.
// Native clang vector types (ext_vector_type) because
// __builtin_nontemporal_store rejects HIP_vector_type<float,4>.

typedef float f32x4 __attribute__((ext_vector_type(4)));
typedef int   i32x4 __attribute__((ext_vector_type(4)));

__device__ __forceinline__ float sel3(float a, float b, float c, int p) {
    // p in {0,1,2}: two v_cndmask
    return (p == 0) ? a : ((p == 1) ? b : c);
}

__global__ __launch_bounds__(256) void PerPixelChannelPermutation_kernel(
    const f32x4* __restrict__ img4, const i32x4* __restrict__ perm4,
    f32x4* __restrict__ out4, int half_chunks) {
    const int t = blockIdx.x * blockDim.x + threadIdx.x;
    if (t >= half_chunks) return;
    const long baseA = (long)t * 3;
    const long baseB = (long)(t + half_chunks) * 3;

    // Issue all 12 loads up front (independent chains -> high MLP).
    const f32x4 a0 = img4[baseA + 0];
    const f32x4 a1 = img4[baseA + 1];
    const f32x4 a2 = img4[baseA + 2];
    const f32x4 b0 = img4[baseB + 0];
    const f32x4 b1 = img4[baseB + 1];
    const f32x4 b2 = img4[baseB + 2];
    const i32x4 pa0 = perm4[baseA + 0];
    const i32x4 pa1 = perm4[baseA + 1];
    const i32x4 pa2 = perm4[baseA + 2];
    const i32x4 pb0 = perm4[baseB + 0];
    const i32x4 pb1 = perm4[baseB + 1];
    const i32x4 pb2 = perm4[baseB + 2];

    f32x4 oa0, oa1, oa2, ob0, ob1, ob2;

    // Chunk A: pixels 0..3 over (a0,a1,a2)
    oa0.x = sel3(a0.x, a0.y, a0.z, pa0.x);
    oa0.y = sel3(a0.x, a0.y, a0.z, pa0.y);
    oa0.z = sel3(a0.x, a0.y, a0.z, pa0.z);
    oa0.w = sel3(a0.w, a1.x, a1.y, pa0.w);
    oa1.x = sel3(a0.w, a1.x, a1.y, pa1.x);
    oa1.y = sel3(a0.w, a1.x, a1.y, pa1.y);
    oa1.z = sel3(a1.z, a1.w, a2.x, pa1.z);
    oa1.w = sel3(a1.z, a1.w, a2.x, pa1.w);
    oa2.x = sel3(a1.z, a1.w, a2.x, pa2.x);
    oa2.y = sel3(a2.y, a2.z, a2.w, pa2.y);
    oa2.z = sel3(a2.y, a2.z, a2.w, pa2.z);
    oa2.w = sel3(a2.y, a2.z, a2.w, pa2.w);

    // Chunk B: pixels 0..3 over (b0,b1,b2)
    ob0.x = sel3(b0.x, b0.y, b0.z, pb0.x);
    ob0.y = sel3(b0.x, b0.y, b0.z, pb0.y);
    ob0.z = sel3(b0.x, b0.y, b0.z, pb0.z);
    ob0.w = sel3(b0.w, b1.x, b1.y, pb0.w);
    ob1.x = sel3(b0.w, b1.x, b1.y, pb1.x);
    ob1.y = sel3(b0.w, b1.x, b1.y, pb1.y);
    ob1.z = sel3(b1.z, b1.w, b2.x, pb1.z);
    ob1.w = sel3(b1.z, b1.w, b2.x, pb1.w);
    ob2.x = sel3(b1.z, b1.w, b2.x, pb2.x);
    ob2.y = sel3(b2.y, b2.z, b2.w, pb2.y);
    ob2.z = sel3(b2.y, b2.z, b2.w, pb2.z);
    ob2.w = sel3(b2.y, b2.z, b2.w, pb2.w);

    // Non-temporal stores: write-once stream.
    __builtin_nontemporal_store(oa0, &out4[baseA + 0]);
    __builtin_nontemporal_store(oa1, &out4[baseA + 1]);
    __builtin_nontemporal_store(oa2, &out4[baseA + 2]);
    __builtin_nontemporal_store(ob0, &out4[baseB + 0]);
    __builtin_nontemporal_store(ob1, &out4[baseB + 1]);
    __builtin_nontemporal_store(ob2, &out4[baseB + 2]);
}

extern "C" void kernel_launch(void* const* d_in, const int* in_sizes, int n_in,
                              void* d_out, int out_size, void* d_ws, size_t ws_size,
                              hipStream_t stream) {
    const f32x4* img4  = (const f32x4*)d_in[0];
    const i32x4* perm4 = (const i32x4*)d_in[1];
    f32x4*       out4  = (f32x4*)d_out;

    const int n_elems     = in_sizes[0];       // 4096*4096*3
    const int n_chunks    = n_elems / 12;      // 48B chunks (4 pixels each)
    const int half_chunks = n_chunks / 2;      // 2 chunks per thread

    const int block = 256;
    const int grid  = (half_chunks + block - 1) / block;
    PerPixelChannelPermutation_kernel<<<grid, block, 0, stream>>>(
        img4, perm4, out4, half_chunks);
}

// Round 4
// 427.624 us; speedup vs baseline: 1.0939x; 1.0939x over previous
//
#include <hip/hip_runtime.h>

// out[n] = image[3*(n/3) + perm[n]], N = 4096*4096*3 floats.
// R4: fully-coalesced mapping. One thread per OUTPUT float4 (chunk c):
// every global load/store is lane-contiguous (1024B per wave instr),
// unlike R1-R3's stride-48 pattern (48 cache lines per instr).
// The permutation for elements 4c..4c+3 only needs img[4c-2 .. 4c+5]:
// own float4 + 2 floats from prev lane + 2 from next lane via __shfl.
// Wave-edge lanes (0,63) patch neighbors with predicated scalar loads.

typedef float f32x4 __attribute__((ext_vector_type(4)));
typedef int   i32x4 __attribute__((ext_vector_type(4)));

__device__ __forceinline__ float sel8(float c0, float c1, float c2, float c3,
                                      float c4, float c5, float c6, float c7,
                                      int idx) {
    // 8-way select, 7 v_cndmask tree (idx in [0,7])
    float s01 = (idx & 1) ? c1 : c0;
    float s23 = (idx & 1) ? c3 : c2;
    float s45 = (idx & 1) ? c5 : c4;
    float s67 = (idx & 1) ? c7 : c6;
    float s03 = (idx & 2) ? s23 : s01;
    float s47 = (idx & 2) ? s67 : s45;
    return (idx & 4) ? s47 : s03;
}

__global__ __launch_bounds__(256) void PerPixelChannelPermutation_kernel(
    const float* __restrict__ img, const i32x4* __restrict__ perm4,
    f32x4* __restrict__ out4, int nchunks, int n_elems) {
    const int c = blockIdx.x * blockDim.x + threadIdx.x;
    if (c >= nchunks) return;
    const int c4 = c * 4;

    const f32x4* img4 = (const f32x4*)img;
    const f32x4 v = img4[c];      // img[4c .. 4c+3], coalesced
    const i32x4 q = perm4[c];     // perm[4c .. 4c+3], coalesced

    // Neighbor floats via cross-lane shuffle (wave64).
    float pm2 = __shfl_up(v.z, 1);    // img[4c-2]
    float pm1 = __shfl_up(v.w, 1);    // img[4c-1]
    float nx0 = __shfl_down(v.x, 1);  // img[4c+4]
    float nx1 = __shfl_down(v.y, 1);  // img[4c+5]

    const int lane = threadIdx.x & 63;
    if (lane == 0) {
        // prev chunk belongs to another wave; load directly.
        // At c==0 these candidates are unreachable (idx>=2), clamp is safe.
        int b = c4 - 2; if (b < 0) b = 0;
        pm2 = img[b];
        pm1 = img[b + 1];
    }
    if (lane == 63) {
        // At the last chunk these candidates are unreachable, clamp is safe.
        int b = c4 + 4; if (b > n_elems - 2) b = n_elems - 2;
        nx0 = img[b];
        nx1 = img[b + 1];
    }

    // idx_k = (pixel_base(4c+k) - 4c) + 2 + perm_k  in [0,7]
    // candidates: [pm2, pm1, v.x, v.y, v.z, v.w, nx0, nx1] = img[4c-2 .. 4c+5]
    f32x4 o;
    {
        const unsigned n = (unsigned)(c4 + 0);
        const int idx = (int)((n / 3u) * 3u) - c4 + 2 + q.x;
        o.x = sel8(pm2, pm1, v.x, v.y, v.z, v.w, nx0, nx1, idx);
    }
    {
        const unsigned n = (unsigned)(c4 + 1);
        const int idx = (int)((n / 3u) * 3u) - c4 + 2 + q.y;
        o.y = sel8(pm2, pm1, v.x, v.y, v.z, v.w, nx0, nx1, idx);
    }
    {
        const unsigned n = (unsigned)(c4 + 2);
        const int idx = (int)((n / 3u) * 3u) - c4 + 2 + q.z;
        o.z = sel8(pm2, pm1, v.x, v.y, v.z, v.w, nx0, nx1, idx);
    }
    {
        const unsigned n = (unsigned)(c4 + 3);
        const int idx = (int)((n / 3u) * 3u) - c4 + 2 + q.w;
        o.w = sel8(pm2, pm1, v.x, v.y, v.z, v.w, nx0, nx1, idx);
    }

    out4[c] = o;  // coalesced
}

extern "C" void kernel_launch(void* const* d_in, const int* in_sizes, int n_in,
                              void* d_out, int out_size, void* d_ws, size_t ws_size,
                              hipStream_t stream) {
    const float* img   = (const float*)d_in[0];
    const i32x4* perm4 = (const i32x4*)d_in[1];
    f32x4*       out4  = (f32x4*)d_out;

    const int n_elems = in_sizes[0];   // 4096*4096*3 = 50,331,648
    const int nchunks = n_elems / 4;   // one thread per output float4

    const int block = 256;
    const int grid  = (nchunks + block - 1) / block;
    PerPixelChannelPermutation_kernel<<<grid, block, 0, stream>>>(
        img, perm4, out4, nchunks, n_elems);
}